// Round 11
// baseline (2271.591 us; speedup 1.0000x reference)
//
#include <hip/hip_runtime.h>

#define EMBD 256
#define HIDD 512
#define SEQL 512
#define NRNG 8            // rings of 16 batch rows
#define NCG  8            // col-group WGs per ring (64 cols each)
#define THR  512
#define SPIN_CAP 65536

typedef unsigned int u32;
typedef unsigned long long u64;
typedef _Float16 half8 __attribute__((ext_vector_type(8)));
typedef _Float16 h2 __attribute__((ext_vector_type(2)));
typedef float f32x4 __attribute__((ext_vector_type(4)));

#define WS_WA_OFF 0          // 786432 B : W frags [MT 0..31][chunk 0..23][64 lanes][4 dw]
#define WS_X_OFF  786432     // 524288 B : u64 X[2 slots][8 rings][16 rows][256 pairs]

static __device__ __forceinline__ u32 packh2(float a, float b) {
    _Float16 lo = (_Float16)a, hi = (_Float16)b;
    return (u32)__builtin_bit_cast(unsigned short, lo)
         | ((u32)__builtin_bit_cast(unsigned short, hi) << 16);
}

__global__ __launch_bounds__(1024)
void init_X(u64* __restrict__ X) {
    X[(size_t)blockIdx.x * 1024 + threadIdx.x] = 0ull;   // grid 64 -> 65536 u64
}

// W (f32 [768][512]) -> A-frags for mfma_f32_16x16x32_f16.
// Frag (MT, c): lane l, dword d = f16 pair (k0,k0+1), k0 = 32c + 8*(l>>4) + 2d,
// hcol = MT*16 + (l&15). Grid 768 (= MT*24+c) x 256.
__global__ __launch_bounds__(256)
void convert_WA(const float* __restrict__ W, u32* __restrict__ WA) {
    const int b = blockIdx.x;
    const int mt = b / 24, c = b % 24;
    const int tid = threadIdx.x, l = tid >> 2, d = tid & 3;
    const int k0 = 32 * c + 8 * (l >> 4) + 2 * d;
    const int hc = mt * 16 + (l & 15);
    WA[b * 256 + tid] = packh2(W[(size_t)k0 * HIDD + hc],
                               W[(size_t)(k0 + 1) * HIDD + hc]);
}

// 64 WGs (ring, cg) x 512 thr (8 waves = 2/SIMD). WG: 16 rows x 64 cols.
// Wave w: mt = w&3 (M-tile MT = cg*4+mt), kh = w>>2 (K-half: kh0 = 8 emb + state 0-3,
// kh1 = state 4-15). Wave w stages state chunks {2w, 2w+1}; wave w==cg gets its
// chunks via LDS from the reduce phase (no LLC RT). 2-way K-reduce in LDS.
__global__ __launch_bounds__(THR, 1)
void rnn_v11(const int*   __restrict__ tokens,
             const float* __restrict__ V,
             const u32*   __restrict__ WA,
             const float* __restrict__ bias,
             const float* __restrict__ Wd,
             const float* __restrict__ bd,
             float*       __restrict__ y,
             u64*         __restrict__ X)
{
    __shared__ uint4 Sst[16][64];     // state B-frags (u32 payload), 16 KB
    __shared__ uint4 Sem[2][8][64];   // emb B-frags, double-buffered, 16 KB
    __shared__ f32x4 P[2][4][64];     // K-half partials, 8 KB
    __shared__ float yp[16][17];

    const int tid  = threadIdx.x;
    const int wg   = blockIdx.x;
    const int ring = wg >> 3, cg = wg & 7;
    const int w    = tid >> 6, l = tid & 63;
    const int g    = l >> 4, row = l & 15;
    const int mt   = w & 3, kh = w >> 2;
    const int MT   = cg * 4 + mt;

    // W frags: 12 chunks x 4 dwords = 48 VGPR
    uint4 wa[12];
    #pragma unroll
    for (int j = 0; j < 12; ++j)
        wa[j] = *(const uint4*)&WA[((MT * 24 + kh * 12 + j) * 64 + l) * 4];

    // emb staging role: chunk ec = w, lane el = l -> (row er, k-group eg)
    const int ec = w, el = l, eg = el >> 4, er = el & 15;

    // reduce role (tid < 256)
    const int mt_r = tid >> 6, l_r = tid & 63, g_r = l_r >> 4, row_r = l_r & 15;
    const int MT_r = cg * 4 + mt_r;
    float4 bias4 = make_float4(0.f, 0.f, 0.f, 0.f);
    if (tid < 256) bias4 = *(const float4*)&bias[MT_r * 16 + 4 * g_r];

    // zero Sst (own chunks must be 0 for t=0; rest overwritten by staging)
    for (int i = tid; i < 16 * 64; i += THR) ((uint4*)Sst)[i] = (uint4){0u, 0u, 0u, 0u};

    // prologue: emb(0) -> Sem[0]
    {
        const int tok = tokens[(ring * 16 + er) * SEQL + 0];
        const float4 e0 = *(const float4*)&V[(size_t)tok * EMBD + 32 * ec + 8 * eg];
        const float4 e1 = *(const float4*)&V[(size_t)tok * EMBD + 32 * ec + 8 * eg + 4];
        Sem[0][ec][el] = (uint4){packh2(e0.x, e0.y), packh2(e0.z, e0.w),
                                 packh2(e1.x, e1.y), packh2(e1.z, e1.w)};
    }
    __syncthreads();

    const bool stager = (w != cg);

    for (int t = 0; t < SEQL; ++t) {
        const int slot_r = (t + 1) & 1;   // holds state(t-1), tag t
        const int slot_w = t & 1;         // receives state(t), tag t+1

        // ---- P1: speculative X loads for chunks {2w, 2w+1} ----
        const u64* Xr = X + (((size_t)slot_r * NRNG + ring) * 16 + row) * 256;
        u64 sv[8];
        if (stager) {
            #pragma unroll
            for (int jj = 0; jj < 2; ++jj) {
                const int p = (2 * w + jj) * 16 + 4 * g;
                #pragma unroll
                for (int d = 0; d < 4; ++d)
                    sv[jj * 4 + d] = __hip_atomic_load(Xr + p + d,
                                         __ATOMIC_RELAXED, __HIP_MEMORY_SCOPE_AGENT);
            }
        }

        // ---- P2: emb(t+1) V loads (recurrence-independent) ----
        const int tn  = (t + 1 < SEQL) ? (t + 1) : (SEQL - 1);
        const int tok = tokens[(ring * 16 + er) * SEQL + tn];
        const float4 e0 = *(const float4*)&V[(size_t)tok * EMBD + 32 * ec + 8 * eg];
        const float4 e1 = *(const float4*)&V[(size_t)tok * EMBD + 32 * ec + 8 * eg + 4];

        // ---- P3: early emb MFMAs (kh0 only) while loads fly ----
        f32x4 c0 = (f32x4){0.f, 0.f, 0.f, 0.f}, c1 = c0;
        if (kh == 0) {
            #pragma unroll
            for (int c = 0; c < 8; ++c) {
                const uint4 B = Sem[slot_w][c][l];
                f32x4& a = (c & 1) ? c1 : c0;
                a = __builtin_amdgcn_mfma_f32_16x16x32_f16(
                        __builtin_bit_cast(half8, wa[c]), __builtin_bit_cast(half8, B),
                        a, 0, 0, 0);
            }
        }

        // ---- P4: validate tags (bounded) + stage frags to LDS ----
        if (stager) {
            bool ok = true;
            #pragma unroll
            for (int i = 0; i < 8; ++i) ok &= ((u32)(sv[i] >> 32) == (u32)t);
            int guard = 0;
            while (!__all(ok) && guard < SPIN_CAP) {
                ++guard;
                __builtin_amdgcn_s_sleep(1);
                #pragma unroll
                for (int jj = 0; jj < 2; ++jj) {
                    const int p = (2 * w + jj) * 16 + 4 * g;
                    #pragma unroll
                    for (int d = 0; d < 4; ++d)
                        sv[jj * 4 + d] = __hip_atomic_load(Xr + p + d,
                                             __ATOMIC_RELAXED, __HIP_MEMORY_SCOPE_AGENT);
                }
                ok = true;
                #pragma unroll
                for (int i = 0; i < 8; ++i) ok &= ((u32)(sv[i] >> 32) == (u32)t);
            }
            Sst[2 * w][l]     = (uint4){(u32)sv[0], (u32)sv[1], (u32)sv[2], (u32)sv[3]};
            Sst[2 * w + 1][l] = (uint4){(u32)sv[4], (u32)sv[5], (u32)sv[6], (u32)sv[7]};
        }
        __syncthreads();   // B1: all 16 state chunk-frags for step t in LDS

        // ---- P5: emb(t+1) pack + write (buffer slot_r; read next step) ----
        Sem[slot_r][ec][el] = (uint4){packh2(e0.x, e0.y), packh2(e0.z, e0.w),
                                      packh2(e1.x, e1.y), packh2(e1.z, e1.w)};

        // ---- P6: state MFMAs ----
        if (kh == 0) {
            #pragma unroll
            for (int j = 0; j < 4; ++j) {
                const uint4 B = Sst[j][l];
                f32x4& a = (j & 1) ? c1 : c0;
                a = __builtin_amdgcn_mfma_f32_16x16x32_f16(
                        __builtin_bit_cast(half8, wa[8 + j]), __builtin_bit_cast(half8, B),
                        a, 0, 0, 0);
            }
        } else {
            #pragma unroll
            for (int j = 0; j < 12; ++j) {
                const uint4 B = Sst[4 + j][l];
                f32x4& a = (j & 1) ? c1 : c0;
                a = __builtin_amdgcn_mfma_f32_16x16x32_f16(
                        __builtin_bit_cast(half8, wa[j]), __builtin_bit_cast(half8, B),
                        a, 0, 0, 0);
            }
        }

        // ---- P7: partials ----
        P[kh][mt][l] = c0 + c1;
        __syncthreads();   // B2

        // ---- P8: K-reduce + bias + tanh + publish (tid < 256) ----
        if (tid < 256) {
            const f32x4 s4 = P[0][mt_r][l_r] + P[1][mt_r][l_r];
            const float t0 = tanhf(s4.x + bias4.x);
            const float t1 = tanhf(s4.y + bias4.y);
            const float t2 = tanhf(s4.z + bias4.z);
            const float t3 = tanhf(s4.w + bias4.w);
            const u32 d0 = packh2(t0, t1), d1 = packh2(t2, t3);
            const int p0 = MT_r * 8 + 2 * g_r;
            const u64 tag = (u64)(u32)(t + 1) << 32;
            u64* dst = X + (((size_t)slot_w * NRNG + ring) * 16 + row_r) * 256 + p0;
            __hip_atomic_store(dst,     tag | d0, __ATOMIC_RELAXED, __HIP_MEMORY_SCOPE_AGENT);
            __hip_atomic_store(dst + 1, tag | d1, __ATOMIC_RELAXED, __HIP_MEMORY_SCOPE_AGENT);
            // own chunks straight into Sst for step t+1 (skip the LLC RT)
            const int s_loc  = p0 >> 4;                       // 2cg or 2cg+1
            const int lanef  = row_r + 16 * ((p0 >> 2) & 3);
            u32* q = (u32*)&Sst[s_loc][lanef] + (p0 & 3);
            q[0] = d0; q[1] = d1;
        }
        // no barrier here: Sst own-writes are post-B2(t), consumed post-B1(t+1)
    }

    // ---- epilogue: cg==0 WG per ring: y = state(511) . Wd + bd ----
    if (cg == 0) {
        if (tid < 256) {
            const int r2 = tid >> 4, q = tid & 15;
            const u64* Xe = X + (((size_t)1 * NRNG + ring) * 16 + r2) * 256 + q * 16;
            u64 vv[16];
            bool ok;
            int guard = 0;
            do {
                #pragma unroll
                for (int i = 0; i < 16; ++i)
                    vv[i] = __hip_atomic_load(Xe + i, __ATOMIC_RELAXED, __HIP_MEMORY_SCOPE_AGENT);
                ok = true;
                #pragma unroll
                for (int i = 0; i < 16; ++i) ok &= ((u32)(vv[i] >> 32) == (u32)SEQL);
                if (__all(ok)) break;
                __builtin_amdgcn_s_sleep(1);
            } while (++guard < SPIN_CAP);
            float accy = 0.f;
            #pragma unroll
            for (int i = 0; i < 16; ++i) {
                const int p = q * 16 + i;
                const float2 wd = *(const float2*)&Wd[2 * p];
                const h2 hv = __builtin_bit_cast(h2, (u32)vv[i]);
                accy += (float)hv.x * wd.x + (float)hv.y * wd.y;
            }
            yp[r2][q] = accy;
        }
        __syncthreads();
        if (tid < 16) {
            float sy = 0.f;
            #pragma unroll
            for (int j = 0; j < 16; ++j) sy += yp[tid][j];
            y[ring * 16 + tid] = sy + bd[0];
        }
    }
}

extern "C" void kernel_launch(void* const* d_in, const int* in_sizes, int n_in,
                              void* d_out, int out_size, void* d_ws, size_t ws_size,
                              hipStream_t stream)
{
    const int*   tokens = (const int*)  d_in[0];
    const float* V      = (const float*)d_in[1];
    const float* W      = (const float*)d_in[2];
    const float* b      = (const float*)d_in[3];
    const float* Wd     = (const float*)d_in[4];
    const float* bd     = (const float*)d_in[5];
    float* y = (float*)d_out;

    u32* WA = (u32*)((char*)d_ws + WS_WA_OFF);
    u64* X  = (u64*)((char*)d_ws + WS_X_OFF);

    hipLaunchKernelGGL(init_X, dim3(64), dim3(1024), 0, stream, X);
    hipLaunchKernelGGL(convert_WA, dim3(768), dim3(256), 0, stream, W, WA);
    hipLaunchKernelGGL(rnn_v11, dim3(64), dim3(THR), 0, stream,
                       tokens, V, WA, b, Wd, bd, y, X);
}

// Round 12
// 1442.209 us; speedup vs baseline: 1.5751x; 1.5751x over previous
//
#include <hip/hip_runtime.h>

#define EMBD 256
#define HIDD 512
#define SEQL 512
#define THR  512

typedef unsigned int u32;
typedef unsigned long long u64;
typedef _Float16 half8 __attribute__((ext_vector_type(8)));
typedef _Float16 h2 __attribute__((ext_vector_type(2)));
typedef float f32x4 __attribute__((ext_vector_type(4)));

#define WS_WA_OFF 0                       // 786432 B : W A-frags [mt 0..31][chunk 0..23][64][4dw]
#define WS_XS_OFF 786432                  // 67108864 B : u64 xs[512 t][128 row][128] (f16 pairs, bias folded)
#define WS_NEED   (786432ull + 67108864ull)

static __device__ __forceinline__ u32 packh2(float a, float b) {
    _Float16 lo = (_Float16)a, hi = (_Float16)b;
    return (u32)__builtin_bit_cast(unsigned short, lo)
         | ((u32)__builtin_bit_cast(unsigned short, hi) << 16);
}

static __device__ __forceinline__ float fast_tanh(float x) {
    x = fminf(10.f, fmaxf(-10.f, x));
    const float e = __expf(2.f * x);
    return (e - 1.f) * __builtin_amdgcn_rcpf(e + 1.f);
}

// W (f32 [768][512]) -> A-frags for mfma_f32_16x16x32_f16.
// Frag (mt, c): lane l, dword d = f16 pair (k0,k0+1), k0 = 32c + 8*(l>>4) + 2d,
// hcol = mt*16 + (l&15). Grid 768 (= mt*24+c) x 256.   [verified R10/R11]
__global__ __launch_bounds__(256)
void convert_WA(const float* __restrict__ W, u32* __restrict__ WA) {
    const int b = blockIdx.x;
    const int mt = b / 24, c = b % 24;
    const int tid = threadIdx.x, l = tid >> 2, d = tid & 3;
    const int k0 = 32 * c + 8 * (l >> 4) + 2 * d;
    const int hc = mt * 16 + (l & 15);
    WA[b * 256 + tid] = packh2(W[(size_t)k0 * HIDD + hc],
                               W[(size_t)(k0 + 1) * HIDD + hc]);
}

// xs[t][row][hcol] = (emb(tok[row][t]) @ Wx)[hcol] + bias[hcol], f16 pairs.
// Grid 4096 (= t*8 + rowblock) x 256 (4 waves; wave w -> 8 hcol-blocks).
__global__ __launch_bounds__(256)
void xproj_gemm(const int*   __restrict__ tokens,
                const float* __restrict__ V,
                const u32*   __restrict__ WA,
                const float* __restrict__ bias,
                u64*         __restrict__ XS)
{
    const int wgid = blockIdx.x;
    const int t = wgid >> 3, rb = wgid & 7;
    const int w = threadIdx.x >> 6, l = threadIdx.x & 63;
    const int g = l >> 4;
    const int row = rb * 16 + (l & 15);

    const int tok = tokens[row * SEQL + t];
    const float* vb = V + (size_t)tok * EMBD;
    uint4 eb[8];
    #pragma unroll
    for (int c = 0; c < 8; ++c) {
        const float4 v1 = *(const float4*)&vb[32 * c + 8 * g];
        const float4 v2 = *(const float4*)&vb[32 * c + 8 * g + 4];
        eb[c].x = packh2(v1.x, v1.y); eb[c].y = packh2(v1.z, v1.w);
        eb[c].z = packh2(v2.x, v2.y); eb[c].w = packh2(v2.z, v2.w);
    }
    #pragma unroll
    for (int i = 0; i < 8; ++i) {
        const int hcb = w * 8 + i;
        f32x4 acc = (f32x4){0.f, 0.f, 0.f, 0.f};
        #pragma unroll
        for (int c = 0; c < 8; ++c) {
            const uint4 a = *(const uint4*)&WA[((hcb * 24 + c) * 64 + l) * 4];
            acc = __builtin_amdgcn_mfma_f32_16x16x32_f16(
                __builtin_bit_cast(half8, a), __builtin_bit_cast(half8, eb[c]),
                acc, 0, 0, 0);
        }
        const float4 b4 = *(const float4*)&bias[hcb * 16 + 4 * g];
        const u64 pk = (u64)packh2(acc.x + b4.x, acc.y + b4.y)
                     | ((u64)packh2(acc.z + b4.z, acc.w + b4.w) << 32);
        XS[(size_t)t * 16384 + (size_t)row * 128 + hcb * 4 + g] = pk;
    }
}

// Fortress: 8 WGs (one ring of 16 rows each) x 512 thr (8 waves, 2/SIMD).
// Wave w: M-tiles w*4..w*4+3 (64 hcols), FULL K=512. Wh: 13 chunks in VGPR,
// 3 chunks in LDS. State double-buffered in LDS as B-frags; 1 barrier/step.
// NO inter-WG communication in the loop.
__global__ __launch_bounds__(THR, 2)
void rnn_fort(const u32*   __restrict__ WA,
              const u64*   __restrict__ XS,
              const float* __restrict__ Wd,
              const float* __restrict__ bd,
              float*       __restrict__ y)
{
    __shared__ uint4 Wlds[32][3][64];   // 96 KB : chunks 13..15 per mt
    __shared__ uint4 Sst[2][16][64];    // 32 KB : state B-frags, dbuf
    __shared__ float yp[16][33];

    const int tid = threadIdx.x, ring = blockIdx.x;
    const int w = tid >> 6, l = tid & 63, g = l >> 4, r = l & 15;
    const int w4 = w * 4;

    // fill Wlds (chunks 21..23 of WA = state chunks 13..15)
    for (int i = tid; i < 32 * 3 * 64; i += THR) {
        const int mt = i / 192, rem = i % 192, cl = rem >> 6, l2 = rem & 63;
        Wlds[mt][cl][l2] = *(const uint4*)&WA[((mt * 24 + 21 + cl) * 64 + l2) * 4];
    }
    // zero state buffers
    for (int i = tid; i < 2 * 16 * 64; i += THR)
        ((uint4*)Sst)[i] = (uint4){0u, 0u, 0u, 0u};

    // Wh register frags: state chunks 0..12 x 4 mt  (208 VGPR)
    uint4 wreg[13][4];
    #pragma unroll
    for (int c = 0; c < 13; ++c)
        #pragma unroll
        for (int i = 0; i < 4; ++i)
            wreg[c][i] = *(const uint4*)&WA[(((w4 + i) * 24 + 8 + c) * 64 + l) * 4];

    const u64* XSb = XS + (size_t)(ring * 16 + r) * 128;
    __syncthreads();

    for (int t = 0; t < SEQL; ++t) {
        const int cur = t & 1, nxt = cur ^ 1;

        // xs loads (issued early; consumed after MFMAs)
        const u64* XSt = XSb + (size_t)t * 16384;
        const u64 xq0 = XSt[(w4 + 0) * 4 + g];
        const u64 xq1 = XSt[(w4 + 1) * 4 + g];
        const u64 xq2 = XSt[(w4 + 2) * 4 + g];
        const u64 xq3 = XSt[(w4 + 3) * 4 + g];

        // MFMA: full K=512 for 4 M-tiles
        f32x4 a0 = (f32x4){0.f,0.f,0.f,0.f}, a1 = a0, a2 = a0, a3 = a0;
        #pragma unroll
        for (int c = 0; c < 13; ++c) {
            const uint4 B = Sst[cur][c][l];
            a0 = __builtin_amdgcn_mfma_f32_16x16x32_f16(
                __builtin_bit_cast(half8, wreg[c][0]), __builtin_bit_cast(half8, B), a0, 0, 0, 0);
            a1 = __builtin_amdgcn_mfma_f32_16x16x32_f16(
                __builtin_bit_cast(half8, wreg[c][1]), __builtin_bit_cast(half8, B), a1, 0, 0, 0);
            a2 = __builtin_amdgcn_mfma_f32_16x16x32_f16(
                __builtin_bit_cast(half8, wreg[c][2]), __builtin_bit_cast(half8, B), a2, 0, 0, 0);
            a3 = __builtin_amdgcn_mfma_f32_16x16x32_f16(
                __builtin_bit_cast(half8, wreg[c][3]), __builtin_bit_cast(half8, B), a3, 0, 0, 0);
        }
        #pragma unroll
        for (int cl = 0; cl < 3; ++cl) {
            const uint4 B = Sst[cur][13 + cl][l];
            a0 = __builtin_amdgcn_mfma_f32_16x16x32_f16(
                __builtin_bit_cast(half8, Wlds[w4 + 0][cl][l]), __builtin_bit_cast(half8, B), a0, 0, 0, 0);
            a1 = __builtin_amdgcn_mfma_f32_16x16x32_f16(
                __builtin_bit_cast(half8, Wlds[w4 + 1][cl][l]), __builtin_bit_cast(half8, B), a1, 0, 0, 0);
            a2 = __builtin_amdgcn_mfma_f32_16x16x32_f16(
                __builtin_bit_cast(half8, Wlds[w4 + 2][cl][l]), __builtin_bit_cast(half8, B), a2, 0, 0, 0);
            a3 = __builtin_amdgcn_mfma_f32_16x16x32_f16(
                __builtin_bit_cast(half8, Wlds[w4 + 3][cl][l]), __builtin_bit_cast(half8, B), a3, 0, 0, 0);
        }

        // tanh(acc + xs) -> pack -> scatter into next B-frag buffer
        #pragma unroll
        for (int i = 0; i < 4; ++i) {
            const f32x4 a = (i == 0) ? a0 : (i == 1) ? a1 : (i == 2) ? a2 : a3;
            const u64 xq = (i == 0) ? xq0 : (i == 1) ? xq1 : (i == 2) ? xq2 : xq3;
            const h2 xl = __builtin_bit_cast(h2, (u32)xq);
            const h2 xh = __builtin_bit_cast(h2, (u32)(xq >> 32));
            const float s0 = fast_tanh(a.x + (float)xl.x);
            const float s1 = fast_tanh(a.y + (float)xl.y);
            const float s2 = fast_tanh(a.z + (float)xh.x);
            const float s3 = fast_tanh(a.w + (float)xh.y);
            const int p0 = (w4 + i) * 16 + 4 * g;        // state col of s0
            const int ct = p0 >> 5, rem = p0 & 31;
            const int gp = rem >> 3, ds = (rem & 7) >> 1; // ds in {0,2}
            u32* qp = (u32*)&Sst[nxt][ct][gp * 16 + r] + ds;
            qp[0] = packh2(s0, s1);
            qp[1] = packh2(s2, s3);
        }
        __syncthreads();   // writes visible; old buffer free for next overwrite
    }

    // epilogue: state(511) is in Sst[0]; y[row] = state . Wd + bd
    {
        const int row = tid & 15, q = tid >> 4;   // q 0..31 -> k in [q*16, q*16+16)
        float part = 0.f;
        #pragma unroll
        for (int jp = 0; jp < 8; ++jp) {
            const int k = q * 16 + 2 * jp;
            const int c = k >> 5, kk = k & 31, gg = kk >> 3, dd = (kk & 7) >> 1;
            const u32 dw = ((const u32*)&Sst[0][c][gg * 16 + row])[dd];
            const h2 hv = __builtin_bit_cast(h2, dw);
            const float2 wd = *(const float2*)&Wd[k];
            part += (float)hv.x * wd.x + (float)hv.y * wd.y;
        }
        yp[row][q] = part;
        __syncthreads();
        if (tid < 16) {
            float s = 0.f;
            #pragma unroll
            for (int j = 0; j < 32; ++j) s += yp[tid][j];
            y[ring * 16 + tid] = s + bd[0];
        }
    }
}

// ---------------- fallback (proven R1 kernel, zero workspace) ----------------
#define KTOT 768
__global__ __launch_bounds__(256, 1)
void rnn_fused_f32(const int*   __restrict__ tokens,
                   const float* __restrict__ V,
                   const float* __restrict__ W,
                   const float* __restrict__ bias,
                   const float* __restrict__ Wd,
                   const float* __restrict__ bd,
                   float*       __restrict__ y)
{
    __shared__ float vcur[2][KTOT];
    __shared__ int   toks[2][SEQL];
    __shared__ float red0[4], red1[4];

    const int tid = threadIdx.x;
    const int c0 = tid * 2, c1 = c0 + 1;
    const int row0 = blockIdx.x * 2;

    for (int i = tid; i < 2 * SEQL; i += 256)
        toks[i >> 9][i & 511] = tokens[row0 * SEQL + i];
    vcur[0][EMBD + c0] = 0.f; vcur[0][EMBD + c1] = 0.f;
    vcur[1][EMBD + c0] = 0.f; vcur[1][EMBD + c1] = 0.f;
    __syncthreads();

    float emb0 = V[(long)toks[0][0] * EMBD + tid];
    float emb1 = V[(long)toks[1][0] * EMBD + tid];
    const float bh0 = bias[c0], bh1 = bias[c1];
    float s00 = 0.f, s01 = 0.f, s10 = 0.f, s11 = 0.f;

    for (int t = 0; t < SEQL; ++t) {
        vcur[0][tid] = emb0;
        vcur[1][tid] = emb1;
        __syncthreads();
        if (t + 1 < SEQL) {
            emb0 = V[(long)toks[0][t + 1] * EMBD + tid];
            emb1 = V[(long)toks[1][t + 1] * EMBD + tid];
        }
        float a000 = 0.f, a001 = 0.f, a010 = 0.f, a011 = 0.f;
        float a100 = 0.f, a101 = 0.f, a110 = 0.f, a111 = 0.f;
        const float* Wp = W + c0;
        #pragma unroll 4
        for (int k = 0; k < KTOT; k += 4) {
            const float4 v0 = *(const float4*)(&vcur[0][k]);
            const float4 v1 = *(const float4*)(&vcur[1][k]);
            const float2 w0 = *(const float2*)(Wp + (size_t)(k + 0) * HIDD);
            const float2 w1 = *(const float2*)(Wp + (size_t)(k + 1) * HIDD);
            const float2 w2 = *(const float2*)(Wp + (size_t)(k + 2) * HIDD);
            const float2 w3 = *(const float2*)(Wp + (size_t)(k + 3) * HIDD);
            a000 = fmaf(v0.x, w0.x, a000);  a001 = fmaf(v0.x, w0.y, a001);
            a010 = fmaf(v1.x, w0.x, a010);  a011 = fmaf(v1.x, w0.y, a011);
            a100 = fmaf(v0.y, w1.x, a100);  a101 = fmaf(v0.y, w1.y, a101);
            a110 = fmaf(v1.y, w1.x, a110);  a111 = fmaf(v1.y, w1.y, a111);
            a000 = fmaf(v0.z, w2.x, a000);  a001 = fmaf(v0.z, w2.y, a001);
            a010 = fmaf(v1.z, w2.x, a010);  a011 = fmaf(v1.z, w2.y, a011);
            a100 = fmaf(v0.w, w3.x, a100);  a101 = fmaf(v0.w, w3.y, a101);
            a110 = fmaf(v1.w, w3.x, a110);  a111 = fmaf(v1.w, w3.y, a111);
        }
        s00 = tanhf(bh0 + a000 + a100);
        s01 = tanhf(bh1 + a001 + a101);
        s10 = tanhf(bh0 + a010 + a110);
        s11 = tanhf(bh1 + a011 + a111);
        __syncthreads();
        vcur[0][EMBD + c0] = s00; vcur[0][EMBD + c1] = s01;
        vcur[1][EMBD + c0] = s10; vcur[1][EMBD + c1] = s11;
    }

    const float wd0 = Wd[c0], wd1 = Wd[c1];
    float q0 = s00 * wd0 + s01 * wd1;
    float q1 = s10 * wd0 + s11 * wd1;
    for (int off = 32; off > 0; off >>= 1) {
        q0 += __shfl_down(q0, off);
        q1 += __shfl_down(q1, off);
    }
    const int wv = tid >> 6, ln = tid & 63;
    if (ln == 0) { red0[wv] = q0; red1[wv] = q1; }
    __syncthreads();
    if (tid == 0) {
        const float bdv = bd[0];
        y[row0 + 0] = red0[0] + red0[1] + red0[2] + red0[3] + bdv;
        y[row0 + 1] = red1[0] + red1[1] + red1[2] + red1[3] + bdv;
    }
}

extern "C" void kernel_launch(void* const* d_in, const int* in_sizes, int n_in,
                              void* d_out, int out_size, void* d_ws, size_t ws_size,
                              hipStream_t stream)
{
    const int*   tokens = (const int*)  d_in[0];
    const float* V      = (const float*)d_in[1];
    const float* W      = (const float*)d_in[2];
    const float* b      = (const float*)d_in[3];
    const float* Wd     = (const float*)d_in[4];
    const float* bd     = (const float*)d_in[5];
    float* y = (float*)d_out;

    if (ws_size >= WS_NEED) {
        u32* WA = (u32*)((char*)d_ws + WS_WA_OFF);
        u64* XS = (u64*)((char*)d_ws + WS_XS_OFF);
        hipLaunchKernelGGL(convert_WA, dim3(768), dim3(256), 0, stream, W, WA);
        hipLaunchKernelGGL(xproj_gemm, dim3(4096), dim3(256), 0, stream, tokens, V, WA, b, XS);
        hipLaunchKernelGGL(rnn_fort, dim3(8), dim3(THR), 0, stream, WA, XS, Wd, bd, y);
    } else {
        hipLaunchKernelGGL(rnn_fused_f32, dim3(64), dim3(256), 0, stream,
                           tokens, V, W, b, Wd, bd, y);
    }
}